// Round 8
// baseline (107.944 us; speedup 1.0000x reference)
//
#include <hip/hip_runtime.h>
#include <math.h>

#define NB 2048
#define NS 200
#define ND 128

typedef __attribute__((ext_vector_type(8))) short bf16x8;
typedef __attribute__((ext_vector_type(4))) float f32x4;

// LDS layout (u32 units)
#define U_W1HI  0                  // 64 x 136 u16 = 4352 u32 (also pass-2 partials later)
#define U_W1LO  4352               // 4352 u32
#define U_Q     8704               // 128 f32
#define U_BIAS  8832               // 64 f32
#define U_B2    8896               // 32 f32
#define U_W3    8928               // 32 f32
#define U_SC    8960               // 208 f32
#define U_WB    9168               // 208 f32
#define U_WRED  9376               // 8 f32
#define U_BP    9384               // 260 f32 (phase0 bias partials)
#define U_TOTAL 9644               // 38576 B -> 4 blocks/CU

union CvtU4 { unsigned int u[4]; bf16x8 v; };

__device__ __forceinline__ unsigned int permhi(unsigned int a, unsigned int b) {
    // {hi16(a) << 16 | hi16(b)}
    return __builtin_amdgcn_perm(a, b, 0x07060302u);
}
__device__ __forceinline__ unsigned int permlo(unsigned int a, unsigned int b) {
    // {lo16(a) << 16 | lo16(b)}
    return __builtin_amdgcn_perm(a, b, 0x05040100u);
}

extern "C" __global__ void __launch_bounds__(256, 4)
tdra_main(const float* __restrict__ query,
          const float* __restrict__ keys,
          const int*   __restrict__ kmask,
          const float* __restrict__ W1,
          const float* __restrict__ b1,
          const float* __restrict__ a1p,
          const float* __restrict__ W2,
          const float* __restrict__ b2,
          const float* __restrict__ a2p,
          const float* __restrict__ W3,
          const float* __restrict__ b3p,
          float* __restrict__ out)
{
    __shared__ __align__(16) unsigned int smem[U_TOTAL];
    unsigned short* W1hi = (unsigned short*)(smem + U_W1HI);
    unsigned short* W1lo = (unsigned short*)(smem + U_W1LO);
    float* qf    = (float*)(smem + U_Q);
    float* biasE = (float*)(smem + U_BIAS);
    float* b2f   = (float*)(smem + U_B2);
    float* w3f   = (float*)(smem + U_W3);
    float* scf   = (float*)(smem + U_SC);
    float* wbf   = (float*)(smem + U_WB);
    float* wred  = (float*)(smem + U_WRED);
    float* bpf   = (float*)(smem + U_BP);

    const int tid = threadIdx.x;
    const int b   = blockIdx.x;
    const float a1 = a1p[0];
    const float a2 = a2p[0];
    const float b3 = b3p[0];

    const int wv = tid >> 6;
    const int c  = tid & 15;
    const int G  = (tid >> 4) & 3;

    // ---------- Phase 0a: q, b2, W3 staging ----------
    if (tid < 32) {
        float4 qv = *(const float4*)(query + (size_t)b * ND + tid * 4);
        *(float4*)(qf + tid * 4) = qv;
    } else if (tid < 64) {
        b2f[tid - 32] = b2[tid - 32];
    } else if (tid < 96) {
        w3f[tid - 64] = W3[tid - 64];
    }

    // A2 = W2^T fragments straight from global (st-invariant, L2-hit)
    bf16x8 A2h[2][2], A2l[2][2];
    #pragma unroll
    for (int jt = 0; jt < 2; ++jt)
        #pragma unroll
        for (int kt = 0; kt < 2; ++kt)
            #pragma unroll
            for (int e = 0; e < 8; ++e) {
                float x = W2[(kt * 32 + 8 * G + e) * 32 + jt * 16 + c];
                unsigned int u  = __float_as_uint(x);
                unsigned int hb = u & 0xFFFF0000u;
                float lof = x - __uint_as_float(hb);
                A2h[jt][kt][e] = (short)(u >> 16);
                A2l[jt][kt][e] = (short)(__float_as_uint(lof) >> 16);
            }
    __syncthreads();

    // ---------- Phase 0b: W1 planes = split(W1a+W1d+q*W1c); bias partials ----
    {
        int h = tid & 63, dg = tid >> 6;
        #pragma unroll 2
        for (int i = 0; i < 8; ++i) {
            int dblk = dg * 8 + i;
            unsigned int hp[2], lp[2];
            #pragma unroll
            for (int jp = 0; jp < 2; ++jp) {
                int d0 = dblk * 4 + 2 * jp;
                float x0 = W1[d0 * 64 + h] + W1[24576 + d0 * 64 + h]
                         + qf[d0] * W1[16384 + d0 * 64 + h];
                float x1 = W1[(d0 + 1) * 64 + h] + W1[24576 + (d0 + 1) * 64 + h]
                         + qf[d0 + 1] * W1[16384 + (d0 + 1) * 64 + h];
                unsigned int u0 = __float_as_uint(x0), u1 = __float_as_uint(x1);
                hp[jp] = permhi(u1, u0);
                float l0 = x0 - __uint_as_float(u0 & 0xFFFF0000u);
                float l1 = x1 - __uint_as_float(u1 & 0xFFFF0000u);
                lp[jp] = permhi(__float_as_uint(l1), __float_as_uint(l0));
            }
            *(uint2*)(W1hi + h * 136 + dblk * 4) = make_uint2(hp[0], hp[1]);
            *(uint2*)(W1lo + h * 136 + dblk * 4) = make_uint2(lp[0], lp[1]);
        }
        int qt = dg;
        const float* pb = W1 + (size_t)(128 + qt * 32) * 64 + h;
        const float* pd = W1 + (size_t)(384 + qt * 32) * 64 + h;
        float p = 0.f;
        #pragma unroll 8
        for (int i = 0; i < 32; ++i)
            p = fmaf(qf[qt * 32 + i], pb[i * 64] - pd[i * 64], p);
        bpf[qt * 65 + h] = p;
    }
    __syncthreads();
    if (tid < 64)
        biasE[tid] = b1[tid] + bpf[tid] + bpf[65 + tid] + bpf[130 + tid] + bpf[195 + tid];
    __syncthreads();

    // ---------- Main: wave wv owns s-tiles st = wv, wv+4, wv+8, (wv+12) ------
    float4 xs[8];
    {
        int r0 = wv * 16 + c; if (r0 > 199) r0 = 199;
        const float* kp = keys + ((size_t)b * NS + r0) * ND + 8 * G;
        #pragma unroll
        for (int q_ = 0; q_ < 4; ++q_) {
            xs[2 * q_]     = *(const float4*)(kp + q_ * 32);
            xs[2 * q_ + 1] = *(const float4*)(kp + q_ * 32 + 4);
        }
    }

    #pragma unroll 1
    for (int st = wv; st < 13; st += 4) {
        const int rr = st * 16 + c;

        // convert keys f32 -> B1 hi/lo frags (perm-packed)
        bf16x8 B1h[4], B1l[4];
        #pragma unroll
        for (int dt = 0; dt < 4; ++dt) {
            float fe[8] = {xs[2*dt].x, xs[2*dt].y, xs[2*dt].z, xs[2*dt].w,
                           xs[2*dt+1].x, xs[2*dt+1].y, xs[2*dt+1].z, xs[2*dt+1].w};
            CvtU4 H, L;
            #pragma unroll
            for (int j = 0; j < 4; ++j) {
                unsigned int u0 = __float_as_uint(fe[2 * j]);
                unsigned int u1 = __float_as_uint(fe[2 * j + 1]);
                H.u[j] = permhi(u1, u0);
                float l0 = fe[2 * j]     - __uint_as_float(u0 & 0xFFFF0000u);
                float l1 = fe[2 * j + 1] - __uint_as_float(u1 & 0xFFFF0000u);
                L.u[j] = permhi(__float_as_uint(l1), __float_as_uint(l0));
            }
            B1h[dt] = H.v;
            B1l[dt] = L.v;
        }

        // prefetch next tile's keys (hidden under GEMM1+GEMM2)
        if (st + 4 < 13) {
            int rn = (st + 4) * 16 + c; if (rn > 199) rn = 199;
            const float* kp = keys + ((size_t)b * NS + rn) * ND + 8 * G;
            #pragma unroll
            for (int q_ = 0; q_ < 4; ++q_) {
                xs[2 * q_]     = *(const float4*)(kp + q_ * 32);
                xs[2 * q_ + 1] = *(const float4*)(kp + q_ * 32 + 4);
            }
        }

        // GEMM1': acc1[ht] = bias + W1eff^T x K^T
        f32x4 acc1[4];
        #pragma unroll
        for (int ht = 0; ht < 4; ++ht)
            acc1[ht] = *(const f32x4*)(biasE + 16 * ht + 4 * G);
        #pragma unroll
        for (int dt = 0; dt < 4; ++dt) {
            #pragma unroll
            for (int ht = 0; ht < 4; ++ht) {
                int idx = (16 * ht + c) * 136 + 32 * dt + 8 * G;
                bf16x8 A1h = *(const bf16x8*)(W1hi + idx);
                bf16x8 A1l = *(const bf16x8*)(W1lo + idx);
                acc1[ht] = __builtin_amdgcn_mfma_f32_16x16x32_bf16(A1h, B1h[dt], acc1[ht], 0, 0, 0);
                acc1[ht] = __builtin_amdgcn_mfma_f32_16x16x32_bf16(A1h, B1l[dt], acc1[ht], 0, 0, 0);
                acc1[ht] = __builtin_amdgcn_mfma_f32_16x16x32_bf16(A1l, B1h[dt], acc1[ht], 0, 0, 0);
            }
        }

        // PReLU -> packed hi|lo h1 (perm)
        unsigned int p[4][4];
        #pragma unroll
        for (int ht = 0; ht < 4; ++ht)
            #pragma unroll
            for (int r = 0; r < 4; ++r) {
                float v = acc1[ht][r];
                v = fmaxf(v, 0.f) + a1 * fminf(v, 0.f);
                unsigned int u = __float_as_uint(v);
                float lof = v - __uint_as_float(u & 0xFFFF0000u);
                p[ht][r] = permhi(__float_as_uint(lof), u);  // lo<<16 | hi
            }

        // GEMM2': shfl-transpose h1 into B2 frags; acc2 init with b2
        f32x4 acc2[2];
        acc2[0] = *(const f32x4*)(b2f + 4 * G);
        acc2[1] = *(const f32x4*)(b2f + 16 + 4 * G);
        const int srcbase = ((tid & 16) ? 32 : 0) + c;
        #pragma unroll
        for (int kt = 0; kt < 2; ++kt) {
            unsigned int q[8];
            #pragma unroll
            for (int half = 0; half < 2; ++half) {
                int src = srcbase + half * 16;
                #pragma unroll
                for (int r = 0; r < 4; ++r) {
                    unsigned int v0 = (unsigned int)__shfl((int)p[2 * kt][r], src, 64);
                    unsigned int v1 = (unsigned int)__shfl((int)p[2 * kt + 1][r], src, 64);
                    q[half * 4 + r] = (tid & 32) ? v1 : v0;
                }
            }
            CvtU4 BH, BL;
            #pragma unroll
            for (int j = 0; j < 4; ++j) {
                BH.u[j] = permlo(q[2 * j + 1], q[2 * j]);
                BL.u[j] = permhi(q[2 * j + 1], q[2 * j]);
            }
            #pragma unroll
            for (int jt = 0; jt < 2; ++jt) {
                acc2[jt] = __builtin_amdgcn_mfma_f32_16x16x32_bf16(A2h[jt][kt], BH.v, acc2[jt], 0, 0, 0);
                acc2[jt] = __builtin_amdgcn_mfma_f32_16x16x32_bf16(A2h[jt][kt], BL.v, acc2[jt], 0, 0, 0);
                acc2[jt] = __builtin_amdgcn_mfma_f32_16x16x32_bf16(A2l[jt][kt], BH.v, acc2[jt], 0, 0, 0);
            }
        }

        // scores: PReLU + W3-dot in-lane, reduce over G halves
        float sv = 0.f;
        #pragma unroll
        for (int jt = 0; jt < 2; ++jt)
            #pragma unroll
            for (int r = 0; r < 4; ++r) {
                float v = acc2[jt][r];
                v = fmaxf(v, 0.f) + a2 * fminf(v, 0.f);
                sv = fmaf(v, w3f[jt * 16 + 4 * G + r], sv);
            }
        sv += __shfl_xor(sv, 16, 64);
        sv += __shfl_xor(sv, 32, 64);
        if ((tid & 48) == 0 && rr < NS) scf[rr] = sv + b3;
    }
    __syncthreads();

    // ---------- decay + mask + softmax ----------
    float scval = -INFINITY;
    if (tid < NS) {
        if (kmask[(size_t)b * NS + tid] != 0)
            scval = scf[tid] * expf(0.1f * (float)(tid - (NS - 1)));
    }
    const int wid = tid >> 6, lane = tid & 63;
    float mx = scval;
    #pragma unroll
    for (int o = 32; o > 0; o >>= 1) mx = fmaxf(mx, __shfl_xor(mx, o, 64));
    if (lane == 0) wred[wid] = mx;
    __syncthreads();
    float M = fmaxf(fmaxf(wred[0], wred[1]), fmaxf(wred[2], wred[3]));
    float e = (M > -INFINITY) ? expf(scval - M) : 0.f;
    float ssum = e;
    #pragma unroll
    for (int o = 32; o > 0; o >>= 1) ssum += __shfl_xor(ssum, o, 64);
    if (lane == 0) wred[4 + wid] = ssum;
    __syncthreads();
    float SUM = wred[4] + wred[5] + wred[6] + wred[7];
    float wv_ = (SUM > 0.f) ? (e / SUM) : 0.f;
    if (tid < NS) {
        wbf[tid] = wv_;
        out[(size_t)NB * ND + (size_t)b * NS + tid] = wv_;
    }
    __syncthreads();

    // ---------- pass 2: weighted_sum = w @ keys (float4-vectorized) ----------
    // partials alias the dead W1hi plane: 8 groups x 128 d
    float* part = (float*)(smem + U_W1HI);
    {
        const int dq = tid & 31, sg = tid >> 5;       // d = 4*dq.., s = sg*25..
        const float* kp = keys + ((size_t)b * NS + sg * 25) * ND + dq * 4;
        float ax = 0.f, ay = 0.f, az = 0.f, aw = 0.f;
        #pragma unroll 5
        for (int i = 0; i < 25; ++i) {
            float ww = wbf[sg * 25 + i];
            float4 kv = *(const float4*)(kp + (size_t)i * ND);
            ax = fmaf(ww, kv.x, ax);
            ay = fmaf(ww, kv.y, ay);
            az = fmaf(ww, kv.z, az);
            aw = fmaf(ww, kv.w, aw);
        }
        *(float4*)(part + sg * 128 + dq * 4) = make_float4(ax, ay, az, aw);
    }
    __syncthreads();
    if (tid < 128) {
        float s = 0.f;
        #pragma unroll
        for (int g = 0; g < 8; ++g) s += part[g * 128 + tid];
        out[(size_t)b * ND + tid] = s;
    }
}

extern "C" void kernel_launch(void* const* d_in, const int* in_sizes, int n_in,
                              void* d_out, int out_size, void* d_ws, size_t ws_size,
                              hipStream_t stream) {
    (void)in_sizes; (void)n_in; (void)d_ws; (void)ws_size; (void)out_size;
    const float* query = (const float*)d_in[0];
    const float* keys  = (const float*)d_in[1];
    const int*   kmask = (const int*)d_in[2];
    const float* W1 = (const float*)d_in[3];
    const float* b1 = (const float*)d_in[4];
    const float* a1 = (const float*)d_in[5];
    const float* W2 = (const float*)d_in[6];
    const float* b2 = (const float*)d_in[7];
    const float* a2 = (const float*)d_in[8];
    const float* W3 = (const float*)d_in[9];
    const float* b3 = (const float*)d_in[10];
    float* out = (float*)d_out;

    hipLaunchKernelGGL(tdra_main, dim3(NB), dim3(256), 0, stream,
                       query, keys, kmask, W1, b1, a1, W2, b2, a2, W3, b3, out);
}